// Round 1
// baseline (1638.711 us; speedup 1.0000x reference)
//
#include <hip/hip_runtime.h>
#include <stdint.h>

typedef unsigned long long u64;

#define BATCH 16384
#define IND   768
#define HID   4096
#define NOUT  10
#define EPS   1e-5f

// ---------------------------------------------------------------------------
// Pack sign bits: bit=1  <=>  value < 0.  One wave per row, ballot per 64 cols.
// ---------------------------------------------------------------------------
__global__ void pack_sign_kernel(const float* __restrict__ src, int ld, int nwords,
                                 int nrows, u64* __restrict__ dst) {
    int gt   = blockIdx.x * blockDim.x + threadIdx.x;
    int wave = gt >> 6;
    int lane = gt & 63;
    if (wave >= nrows) return;
    const float* row = src + (size_t)wave * ld;
    u64* drow = dst + (size_t)wave * nwords;
    for (int w = 0; w < nwords; ++w) {
        float v = row[(w << 6) + lane];
        u64 m = __ballot(v < 0.0f);
        if (lane == 0) drow[w] = m;
    }
}

// ---------------------------------------------------------------------------
// Binarized GEMM (M=16384, N=4096) + bias + BN(eval) + sign -> packed output.
// C[m,n] = kfull - 2*popc(A[m,:] ^ W[n,:]); y = (C+bias - mu)*g*rsqrt(v+eps)+be
// Block tile 128x128, 256 threads, 8x8 accumulators per thread.
// Thread cols are interleaved (tn + 16*j) for conflict-free LDS B reads.
// ---------------------------------------------------------------------------
template <int KC>
__global__ __launch_bounds__(256, 2) void bgemm_bn_sign(
    const u64* __restrict__ Ap, int kwA,   // A packed [M][kwA]
    const u64* __restrict__ Wp,            // W packed [4096][kwA]
    int kfull,
    const float* __restrict__ bias, const float* __restrict__ gam,
    const float* __restrict__ bet,  const float* __restrict__ mu,
    const float* __restrict__ var,
    u64* __restrict__ Op)                  // out packed [M][64]
{
    constexpr int STR = KC + 1;            // +1 word pad: A reads 2-way (free)
    __shared__ u64 As[128 * STR];
    __shared__ u64 Bs[128 * STR];
    __shared__ unsigned char smask[128 * 128];

    const int tid = threadIdx.x;
    const int bm  = blockIdx.x >> 5;       // 128 row blocks
    const int bn  = blockIdx.x & 31;       // 32 col blocks
    const int m0  = bm << 7;
    const int n0  = bn << 7;

    const int tn  = tid & 15;
    const int tg  = tid >> 4;              // row group 0..15
    const int rm0 = tg << 3;

    unsigned acc[8][8];
    #pragma unroll
    for (int i = 0; i < 8; ++i)
        #pragma unroll
        for (int j = 0; j < 8; ++j) acc[i][j] = 0u;

    const int nchunks = kwA / KC;
    for (int c = 0; c < nchunks; ++c) {
        const int k0 = c * KC;
        #pragma unroll
        for (int idx = tid; idx < 128 * KC; idx += 256) {
            int r = idx / KC, w = idx - r * KC;
            As[r * STR + w] = Ap[(size_t)(m0 + r) * kwA + k0 + w];
            Bs[r * STR + w] = Wp[(size_t)(n0 + r) * kwA + k0 + w];
        }
        __syncthreads();

        for (int kw = 0; kw < KC; ++kw) {
            u64 a[8], b[8];
            #pragma unroll
            for (int i = 0; i < 8; ++i) a[i] = As[(rm0 + i) * STR + kw];
            #pragma unroll
            for (int j = 0; j < 8; ++j) b[j] = Bs[(tn + (j << 4)) * STR + kw];
            #pragma unroll
            for (int i = 0; i < 8; ++i)
                #pragma unroll
                for (int j = 0; j < 8; ++j)
                    acc[i][j] += (unsigned)__popcll(a[i] ^ b[j]);
        }
        __syncthreads();
    }

    // epilogue: BN sign bits into LDS byte mask
    #pragma unroll
    for (int j = 0; j < 8; ++j) {
        int n = n0 + tn + (j << 4);
        float sc = gam[n] * rsqrtf(var[n] + EPS);
        float bj = bias[n], mj = mu[n], ej = bet[n];
        #pragma unroll
        for (int i = 0; i < 8; ++i) {
            float h = (float)(kfull - 2 * (int)acc[i][j]) + bj;
            float y = (h - mj) * sc + ej;
            smask[((rm0 + i) << 7) + tn + (j << 4)] = (y < 0.0f) ? 1 : 0;
        }
    }
    __syncthreads();

    // pack 64 sign bytes -> one u64 per (row, half); 256 threads = 128 rows x 2
    {
        int r = tid >> 1, h = tid & 1;
        const u64* q = (const u64*)&smask[(r << 7) + (h << 6)];
        u64 word = 0;
        #pragma unroll
        for (int t = 0; t < 8; ++t) {
            u64 bits8 = (q[t] * 0x0102040810204080ULL) >> 56;  // byte k -> bit k
            word |= bits8 << (t << 3);
        }
        Op[(size_t)(m0 + r) * 64 + (n0 >> 6) + h] = word;
    }
}

// ---------------------------------------------------------------------------
// Final layer: N=10, K=4096 words=64. One wave per row; wave-reduce 10 dots,
// BN, log_softmax, write 10 outputs.
// ---------------------------------------------------------------------------
__global__ void final_layer_kernel(
    const u64* __restrict__ Ap,   // [B][64]
    const u64* __restrict__ Wp,   // [10][64]
    const float* __restrict__ bias, const float* __restrict__ gam,
    const float* __restrict__ bet,  const float* __restrict__ mu,
    const float* __restrict__ var,
    float* __restrict__ out)      // [B][10]
{
    int gt   = blockIdx.x * blockDim.x + threadIdx.x;
    int row  = gt >> 6;
    int lane = gt & 63;
    if (row >= BATCH) return;

    u64 a = Ap[(size_t)row * 64 + lane];
    unsigned p[NOUT];
    #pragma unroll
    for (int j = 0; j < NOUT; ++j)
        p[j] = (unsigned)__popcll(a ^ Wp[j * 64 + lane]);

    #pragma unroll
    for (int j = 0; j < NOUT; ++j) {
        #pragma unroll
        for (int off = 32; off >= 1; off >>= 1)
            p[j] += __shfl_xor(p[j], off, 64);
    }

    float z[NOUT];
    float mx = -1e30f;
    #pragma unroll
    for (int j = 0; j < NOUT; ++j) {
        float h  = (float)(HID - 2 * (int)p[j]) + bias[j];
        float sc = gam[j] * rsqrtf(var[j] + EPS);
        z[j] = (h - mu[j]) * sc + bet[j];
        mx = fmaxf(mx, z[j]);
    }
    float s = 0.0f;
    #pragma unroll
    for (int j = 0; j < NOUT; ++j) s += expf(z[j] - mx);
    float lse = logf(s) + mx;
    if (lane < NOUT) out[(size_t)row * NOUT + lane] = z[lane] - lse;
}

// ---------------------------------------------------------------------------
extern "C" void kernel_launch(void* const* d_in, const int* in_sizes, int n_in,
                              void* d_out, int out_size, void* d_ws, size_t ws_size,
                              hipStream_t stream) {
    (void)in_sizes; (void)n_in; (void)out_size; (void)ws_size;

    const float* x   = (const float*)d_in[0];
    const float* w1  = (const float*)d_in[1];
    const float* b1  = (const float*)d_in[2];
    const float* g1  = (const float*)d_in[3];
    const float* be1 = (const float*)d_in[4];
    const float* m1  = (const float*)d_in[5];
    const float* v1  = (const float*)d_in[6];
    const float* w2  = (const float*)d_in[7];
    const float* b2  = (const float*)d_in[8];
    const float* g2  = (const float*)d_in[9];
    const float* be2 = (const float*)d_in[10];
    const float* m2  = (const float*)d_in[11];
    const float* v2  = (const float*)d_in[12];
    const float* w3  = (const float*)d_in[13];
    const float* b3  = (const float*)d_in[14];
    const float* g3  = (const float*)d_in[15];
    const float* be3 = (const float*)d_in[16];
    const float* m3  = (const float*)d_in[17];
    const float* v3  = (const float*)d_in[18];
    const float* w4  = (const float*)d_in[19];
    const float* b4  = (const float*)d_in[20];
    const float* g4  = (const float*)d_in[21];
    const float* be4 = (const float*)d_in[22];
    const float* m4  = (const float*)d_in[23];
    const float* v4  = (const float*)d_in[24];

    u64* ws  = (u64*)d_ws;
    u64* xp  = ws;                             // 16384*12
    u64* w1p = xp  + (size_t)BATCH * 12;       // 4096*12
    u64* w2p = w1p + (size_t)HID * 12;         // 4096*64
    u64* w3p = w2p + (size_t)HID * 64;         // 4096*64
    u64* w4p = w3p + (size_t)HID * 64;         // 10*64
    u64* a1  = w4p + (size_t)NOUT * 64;        // 16384*64
    u64* a2  = a1  + (size_t)BATCH * 64;       // 16384*64
    u64* a3  = a2  + (size_t)BATCH * 64;       // 16384*64

    // pack inputs & weights (x: ld=784, use first 768 cols)
    pack_sign_kernel<<<BATCH / 4, 256, 0, stream>>>(x, 784, 12, BATCH, xp);
    pack_sign_kernel<<<HID / 4, 256, 0, stream>>>(w1, IND, 12, HID, w1p);
    pack_sign_kernel<<<HID / 4, 256, 0, stream>>>(w2, HID, 64, HID, w2p);
    pack_sign_kernel<<<HID / 4, 256, 0, stream>>>(w3, HID, 64, HID, w3p);
    pack_sign_kernel<<<3, 256, 0, stream>>>(w4, HID, 64, NOUT, w4p);

    // layers 1-3: binarized GEMM + BN + sign -> packed
    bgemm_bn_sign<12><<<4096, 256, 0, stream>>>(xp, 12, w1p, IND,
                                                b1, g1, be1, m1, v1, a1);
    bgemm_bn_sign<16><<<4096, 256, 0, stream>>>(a1, 64, w2p, HID,
                                                b2, g2, be2, m2, v2, a2);
    bgemm_bn_sign<16><<<4096, 256, 0, stream>>>(a2, 64, w3p, HID,
                                                b3, g3, be3, m3, v3, a3);
    // layer 4 + log_softmax
    final_layer_kernel<<<BATCH / 4, 256, 0, stream>>>(a3, w4p,
                                                      b4, g4, be4, m4, v4,
                                                      (float*)d_out);
}

// Round 2
// 1512.560 us; speedup vs baseline: 1.0834x; 1.0834x over previous
//
#include <hip/hip_runtime.h>
#include <stdint.h>

typedef unsigned long long u64;

#define BATCH 16384
#define IND   768
#define HID   4096
#define NOUT  10
#define EPS   1e-5f

// ---------------------------------------------------------------------------
// Pack sign bits: bit=1  <=>  value < 0.  One wave per row, ballot per 64 cols.
// ---------------------------------------------------------------------------
__global__ void pack_sign_kernel(const float* __restrict__ src, int ld, int nwords,
                                 int nrows, u64* __restrict__ dst) {
    int gt   = blockIdx.x * blockDim.x + threadIdx.x;
    int wave = gt >> 6;
    int lane = gt & 63;
    if (wave >= nrows) return;
    const float* row = src + (size_t)wave * ld;
    u64* drow = dst + (size_t)wave * nwords;
    for (int w = 0; w < nwords; ++w) {
        float v = row[(w << 6) + lane];
        u64 m = __ballot(v < 0.0f);
        if (lane == 0) drow[w] = m;
    }
}

// ---------------------------------------------------------------------------
// Binarized GEMM (M=16384, N=4096) + bias + BN(eval) + sign -> packed output.
// C[m,n] = kfull - 2*popc(A[m,:] ^ W[n,:])
// Block tile 128x128, 256 threads, 8x8 accumulators/thread, 2 K-words/round.
// LDS layouts (all reads 16B-aligned b128, <=2-way bank conflicts = free):
//   As column-major: As[kw][row], row-stride STRA=130 (u64)
//   Bs row-major:    Bs[row][kw], row-stride STRB=KC+2 (even)
// ---------------------------------------------------------------------------
template <int KC>
__global__ __launch_bounds__(256, 4) void bgemm_bn_sign(
    const u64* __restrict__ Ap, int kwA,   // A packed [M][kwA]
    const u64* __restrict__ Wp,            // W packed [4096][kwA]
    int kfull,
    const float* __restrict__ bias, const float* __restrict__ gam,
    const float* __restrict__ bet,  const float* __restrict__ mu,
    const float* __restrict__ var,
    u64* __restrict__ Op)                  // out packed [M][64]
{
    constexpr int STRA = 130;              // 128 rows + 2 pad (even, 16B align)
    constexpr int STRB = KC + 2;           // even -> 16B align for kw pairs
    __shared__ u64 As[KC * STRA];
    __shared__ u64 Bs[128 * STRB];
    __shared__ unsigned char smask[128 * 128];

    const int tid = threadIdx.x;
    const int bm  = blockIdx.x >> 5;       // 128 row blocks
    const int bn  = blockIdx.x & 31;       // 32 col blocks
    const int m0  = bm << 7;
    const int n0  = bn << 7;

    const int tn  = tid & 15;
    const int tg  = tid >> 4;              // row group 0..15
    const int rm0 = tg << 3;

    unsigned acc[8][8];
    #pragma unroll
    for (int i = 0; i < 8; ++i)
        #pragma unroll
        for (int j = 0; j < 8; ++j) acc[i][j] = 0u;

    const int nchunks = kwA / KC;
    for (int c = 0; c < nchunks; ++c) {
        const int k0 = c * KC;
        // stage: each thread moves (128*KC)/(256*2) ulonglong2 per array
        #pragma unroll
        for (int it = 0; it < (128 * KC) / 512; ++it) {
            int idx = tid + it * 256;               // u64-pair index
            int r   = idx / (KC / 2);
            int w2  = (idx - r * (KC / 2)) * 2;
            ulonglong2 va = *(const ulonglong2*)&Ap[(size_t)(m0 + r) * kwA + k0 + w2];
            As[w2 * STRA + r]       = va.x;
            As[(w2 + 1) * STRA + r] = va.y;
            ulonglong2 vb = *(const ulonglong2*)&Wp[(size_t)(n0 + r) * kwA + k0 + w2];
            *(ulonglong2*)&Bs[r * STRB + w2] = vb;
        }
        __syncthreads();

        for (int kw = 0; kw < KC; kw += 2) {
            u64 a0[8], a1[8];
            #pragma unroll
            for (int p = 0; p < 4; ++p) {
                ulonglong2 t0 = *(const ulonglong2*)&As[kw * STRA + rm0 + 2 * p];
                ulonglong2 t1 = *(const ulonglong2*)&As[(kw + 1) * STRA + rm0 + 2 * p];
                a0[2 * p] = t0.x; a0[2 * p + 1] = t0.y;
                a1[2 * p] = t1.x; a1[2 * p + 1] = t1.y;
            }
            #pragma unroll
            for (int j = 0; j < 8; ++j) {
                ulonglong2 bb = *(const ulonglong2*)&Bs[(tn + (j << 4)) * STRB + kw];
                #pragma unroll
                for (int i = 0; i < 8; ++i) {
                    u64 x0 = a0[i] ^ bb.x;
                    u64 x1 = a1[i] ^ bb.y;
                    acc[i][j] += (unsigned)(__popcll(x0) + __popcll(x1));
                }
            }
        }
        __syncthreads();
    }

    // epilogue: BN sign bits into LDS byte mask
    #pragma unroll
    for (int j = 0; j < 8; ++j) {
        int n = n0 + tn + (j << 4);
        float sc = gam[n] * rsqrtf(var[n] + EPS);
        float bj = bias[n], mj = mu[n], ej = bet[n];
        #pragma unroll
        for (int i = 0; i < 8; ++i) {
            float h = (float)(kfull - 2 * (int)acc[i][j]) + bj;
            float y = (h - mj) * sc + ej;
            smask[((rm0 + i) << 7) + tn + (j << 4)] = (y < 0.0f) ? 1 : 0;
        }
    }
    __syncthreads();

    // pack 64 sign bytes -> one u64 per (row, half); 256 threads = 128 rows x 2
    {
        int r = tid >> 1, h = tid & 1;
        const u64* q = (const u64*)&smask[(r << 7) + (h << 6)];
        u64 word = 0;
        #pragma unroll
        for (int t = 0; t < 8; ++t) {
            u64 bits8 = (q[t] * 0x0102040810204080ULL) >> 56;  // byte k -> bit k
            word |= bits8 << (t << 3);
        }
        Op[(size_t)(m0 + r) * 64 + (n0 >> 6) + h] = word;
    }
}

// ---------------------------------------------------------------------------
// Final layer: N=10, K=4096 words=64. One wave per row; wave-reduce 10 dots,
// BN, log_softmax, write 10 outputs.
// ---------------------------------------------------------------------------
__global__ void final_layer_kernel(
    const u64* __restrict__ Ap,   // [B][64]
    const u64* __restrict__ Wp,   // [10][64]
    const float* __restrict__ bias, const float* __restrict__ gam,
    const float* __restrict__ bet,  const float* __restrict__ mu,
    const float* __restrict__ var,
    float* __restrict__ out)      // [B][10]
{
    int gt   = blockIdx.x * blockDim.x + threadIdx.x;
    int row  = gt >> 6;
    int lane = gt & 63;
    if (row >= BATCH) return;

    u64 a = Ap[(size_t)row * 64 + lane];
    unsigned p[NOUT];
    #pragma unroll
    for (int j = 0; j < NOUT; ++j)
        p[j] = (unsigned)__popcll(a ^ Wp[j * 64 + lane]);

    #pragma unroll
    for (int j = 0; j < NOUT; ++j) {
        #pragma unroll
        for (int off = 32; off >= 1; off >>= 1)
            p[j] += __shfl_xor(p[j], off, 64);
    }

    float z[NOUT];
    float mx = -1e30f;
    #pragma unroll
    for (int j = 0; j < NOUT; ++j) {
        float h  = (float)(HID - 2 * (int)p[j]) + bias[j];
        float sc = gam[j] * rsqrtf(var[j] + EPS);
        z[j] = (h - mu[j]) * sc + bet[j];
        mx = fmaxf(mx, z[j]);
    }
    float s = 0.0f;
    #pragma unroll
    for (int j = 0; j < NOUT; ++j) s += expf(z[j] - mx);
    float lse = logf(s) + mx;
    if (lane < NOUT) out[(size_t)row * NOUT + lane] = z[lane] - lse;
}

// ---------------------------------------------------------------------------
extern "C" void kernel_launch(void* const* d_in, const int* in_sizes, int n_in,
                              void* d_out, int out_size, void* d_ws, size_t ws_size,
                              hipStream_t stream) {
    (void)in_sizes; (void)n_in; (void)out_size; (void)ws_size;

    const float* x   = (const float*)d_in[0];
    const float* w1  = (const float*)d_in[1];
    const float* b1  = (const float*)d_in[2];
    const float* g1  = (const float*)d_in[3];
    const float* be1 = (const float*)d_in[4];
    const float* m1  = (const float*)d_in[5];
    const float* v1  = (const float*)d_in[6];
    const float* w2  = (const float*)d_in[7];
    const float* b2  = (const float*)d_in[8];
    const float* g2  = (const float*)d_in[9];
    const float* be2 = (const float*)d_in[10];
    const float* m2  = (const float*)d_in[11];
    const float* v2  = (const float*)d_in[12];
    const float* w3  = (const float*)d_in[13];
    const float* b3  = (const float*)d_in[14];
    const float* g3  = (const float*)d_in[15];
    const float* be3 = (const float*)d_in[16];
    const float* m3  = (const float*)d_in[17];
    const float* v3  = (const float*)d_in[18];
    const float* w4  = (const float*)d_in[19];
    const float* b4  = (const float*)d_in[20];
    const float* g4  = (const float*)d_in[21];
    const float* be4 = (const float*)d_in[22];
    const float* m4  = (const float*)d_in[23];
    const float* v4  = (const float*)d_in[24];

    u64* ws  = (u64*)d_ws;
    u64* xp  = ws;                             // 16384*12
    u64* w1p = xp  + (size_t)BATCH * 12;       // 4096*12
    u64* w2p = w1p + (size_t)HID * 12;         // 4096*64
    u64* w3p = w2p + (size_t)HID * 64;         // 4096*64
    u64* w4p = w3p + (size_t)HID * 64;         // 10*64
    u64* a1  = w4p + (size_t)NOUT * 64;        // 16384*64
    u64* a2  = a1  + (size_t)BATCH * 64;       // 16384*64
    u64* a3  = a2  + (size_t)BATCH * 64;       // 16384*64

    // pack inputs & weights (x: ld=784, use first 768 cols)
    pack_sign_kernel<<<BATCH / 4, 256, 0, stream>>>(x, 784, 12, BATCH, xp);
    pack_sign_kernel<<<HID / 4, 256, 0, stream>>>(w1, IND, 12, HID, w1p);
    pack_sign_kernel<<<HID / 4, 256, 0, stream>>>(w2, HID, 64, HID, w2p);
    pack_sign_kernel<<<HID / 4, 256, 0, stream>>>(w3, HID, 64, HID, w3p);
    pack_sign_kernel<<<3, 256, 0, stream>>>(w4, HID, 64, NOUT, w4p);

    // layers 1-3: binarized GEMM + BN + sign -> packed
    bgemm_bn_sign<12><<<4096, 256, 0, stream>>>(xp, 12, w1p, IND,
                                                b1, g1, be1, m1, v1, a1);
    bgemm_bn_sign<16><<<4096, 256, 0, stream>>>(a1, 64, w2p, HID,
                                                b2, g2, be2, m2, v2, a2);
    bgemm_bn_sign<16><<<4096, 256, 0, stream>>>(a2, 64, w3p, HID,
                                                b3, g3, be3, m3, v3, a3);
    // layer 4 + log_softmax
    final_layer_kernel<<<BATCH / 4, 256, 0, stream>>>(a3, w4p,
                                                      b4, g4, be4, m4, v4,
                                                      (float*)d_out);
}